// Round 7
// baseline (177.563 us; speedup 1.0000x reference)
//
#include <hip/hip_runtime.h>

typedef unsigned int uint_t;
typedef unsigned short ushort_t;

constexpr int MAXDEG = 64;   // slots per node row; deg ~ Poisson(16): P(deg >= 64) ~ 3e-22
// R1: cacheline-padding cursor REGRESSED — same-line atomic contention is NOT the issue.
// R2: batching 4 atomics 114->73us — atomic LATENCY chain was ~40us.
// R3: vmcnt-overlap schedule: NULL — fill cost is memory-side THROUGHPUT.
// R4: XCD-sliced edge regions: NULL — the ~51MB write excess tracks the ATOMIC count
//     (800K x 64B fabric transactions each), not edge-store locality.
// R5: gemm2 -> bf16 MFMA split-W: WIN 175->167, absmax unchanged. NT on X staging: regression, reverted.
// R6: pair-gather aggs: small win (~5us) -> aggs are BW-bound at ~6.3TB/s for 435MB of
//     random 256B gathers = at roofline. Bytes irreducible at bf16.
// R7: kill the 800K per-edge global atomics: two-phase LDS-binned CSR build.
//     Phase A: LDS-histogram per 2048-edge block -> 64 global atomics/block -> contiguous
//     (dst,src) runs per coarse bucket (dst>>10). Phase B: one block per bucket builds the
//     64-slot rows for its 1024-node range in LDS, coalesced copy-out + deg[]. gemm1 is a
//     pure GEMM again.

// ---------------- bf16 helpers (RNE) ----------------
static __device__ __forceinline__ uint_t f2bf_bits(float f) {
  uint_t u = __builtin_bit_cast(uint_t, f);
  return (u + 0x7fffu + ((u >> 16) & 1u)) >> 16;
}
static __device__ __forceinline__ uint_t pack_bf2(float lo, float hi) {
  return f2bf_bits(lo) | (f2bf_bits(hi) << 16);
}
static __device__ __forceinline__ float bf_lo(uint_t u) {
  return __builtin_bit_cast(float, u << 16);
}
static __device__ __forceinline__ float bf_hi(uint_t u) {
  return __builtin_bit_cast(float, u & 0xffff0000u);
}

// ---------------- vector types ----------------
typedef __attribute__((ext_vector_type(2))) uint_t v2u;
typedef __attribute__((ext_vector_type(8))) short  short8_t;  // 8 bf16 (4 VGPRs)
typedef __attribute__((ext_vector_type(4))) float  f32x4_t;   // MFMA acc

static __device__ __forceinline__ void stnt_u2(uint_t* p, uint_t a, uint_t b) {
  v2u t; t.x = a; t.y = b;
  __builtin_nontemporal_store(t, (v2u*)p);
}

static inline size_t align256(size_t x) { return (x + 255) & ~(size_t)255; }

// ---------------- Phase A: bin edges into coarse dst-range buckets ----------------
// 2048 edges/block. LDS histogram (64 buckets = nodes >> shift), one global atomic per
// non-empty bucket per block, then contiguous uint2 (dst,src) writes per bucket run.
__global__ __launch_bounds__(256) void bucket_scatter_kernel(
    const int* __restrict__ src, const int* __restrict__ dst,
    uint2* __restrict__ buckets, int* __restrict__ bucketcnt,
    int E, int C, int shift) {
  __shared__ int hist[64];
  __shared__ int base[64];
  const int tid = threadIdx.x;
  const int e0 = blockIdx.x * 2048;

  if (tid < 64) hist[tid] = 0;
  __syncthreads();

  int dd[8], ss[8], slot[8];
#pragma unroll
  for (int i = 0; i < 8; ++i) {
    int e = e0 + tid + i * 256;
    bool ok = (e < E);
    dd[i] = ok ? dst[e] : -1;
    ss[i] = ok ? src[e] : 0;
    slot[i] = ok ? atomicAdd(&hist[dd[i] >> shift], 1) : 0;
  }
  __syncthreads();

  if (tid < 64) {
    int c = hist[tid];
    base[tid] = (c > 0) ? atomicAdd(&bucketcnt[tid], c) : 0;
  }
  __syncthreads();

#pragma unroll
  for (int i = 0; i < 8; ++i) {
    if (dd[i] < 0) continue;
    int b = dd[i] >> shift;
    int pos = base[b] + slot[i];
    if (pos < C)  // capacity guard (P ~ 0 with 1.5x margin)
      buckets[(size_t)b * C + pos] = make_uint2((uint_t)dd[i], (uint_t)ss[i]);
  }
}

// ---------------- Phase B: bucket -> 64-slot CSR rows + deg, all in LDS ----------------
// One block per bucket. WIN-node windows (WIN*64 IdxT rows = 128KB LDS).
template<typename IdxT, int WIN>
__global__ __launch_bounds__(256) void bucket_to_rows_kernel(
    const uint2* __restrict__ buckets, const int* __restrict__ bucketcnt,
    IdxT* __restrict__ edge, int* __restrict__ deg, int Nn, int C, int shift) {
  __shared__ __align__(16) IdxT rows[WIN * MAXDEG];
  __shared__ int cnt[WIN];
  const int tid = threadIdx.x;
  const int b = blockIdx.x;
  const int node0 = b << shift;
  const int RANGE = 1 << shift;
  int ec = bucketcnt[b];
  if (ec > C) ec = C;
  const uint2* bb = buckets + (size_t)b * C;

  for (int w0 = 0; w0 < RANGE; w0 += WIN) {
    for (int i = tid; i < WIN; i += 256) cnt[i] = 0;
    __syncthreads();
    for (int i = tid; i < ec; i += 256) {
      uint2 it = bb[i];
      int local = (int)it.x - node0 - w0;
      if (local >= 0 && local < WIN) {
        int sl = atomicAdd(&cnt[local], 1);
        if (sl < MAXDEG) rows[local * MAXDEG + sl] = (IdxT)it.y;
      }
    }
    __syncthreads();
    const int nbase = node0 + w0;
    constexpr int PER = (MAXDEG * sizeof(IdxT)) / 16;  // uint4 per node row
    const uint4* rv = (const uint4*)rows;
    uint4* ev = (uint4*)(edge + (size_t)nbase * MAXDEG);
    for (int i = tid; i < WIN * PER; i += 256) {
      int node = nbase + i / PER;
      if (node < Nn) ev[i] = rv[i];
    }
    for (int i = tid; i < WIN; i += 256) {
      int node = nbase + i;
      if (node < Nn) deg[node] = cnt[i];  // raw count (may exceed MAXDEG; agg clamps)
    }
    __syncthreads();
  }
}

// ---------------- GEMM1 (pure): outG(bf16) = X @ W1 ----------------
__global__ __launch_bounds__(256) void gemm1_kernel(
    const float* __restrict__ X, const float* __restrict__ W1,
    uint_t* __restrict__ outG, int Nrows) {
  constexpr int BK = 64;
  __shared__ float wlds[BK][128];
  __shared__ float xT[BK][68];

  const int tid = threadIdx.x;
  const int cg = tid & 31;
  const int rl = tid >> 5;
  const int rowbase = blockIdx.x * 64;

  float acc[8][4];
#pragma unroll
  for (int i = 0; i < 8; ++i)
#pragma unroll
    for (int j = 0; j < 4; ++j) acc[i][j] = 0.f;

  for (int k0 = 0; k0 < 128; k0 += BK) {
    __syncthreads();
#pragma unroll
    for (int i = 0; i < 8; ++i) {
      int f = tid + i * 256;
      int kk = f >> 5, cc = f & 31;
      float4 v = ((const float4*)W1)[(size_t)(k0 + kk) * 32 + cc];
      *(float4*)&wlds[kk][cc * 4] = v;
    }
    {
      int r = tid >> 2;
      int rg = rowbase + r;
      int rs = (rg < Nrows) ? rg : (Nrows - 1);
      const float4* xrow = (const float4*)(X + (size_t)rs * 128);
      bool valid = (rg < Nrows);
#pragma unroll
      for (int p = 0; p < 4; ++p) {
        int kf4 = (tid & 3) + p * 4;
        float4 v = xrow[(k0 >> 2) + kf4];
        if (!valid) v = make_float4(0.f, 0.f, 0.f, 0.f);
        int ke = kf4 * 4;
        xT[ke + 0][r] = v.x;
        xT[ke + 1][r] = v.y;
        xT[ke + 2][r] = v.z;
        xT[ke + 3][r] = v.w;
      }
    }
    __syncthreads();
#pragma unroll 8
    for (int kk = 0; kk < BK; ++kk) {
      float4 xa = *(const float4*)&xT[kk][rl * 8];
      float4 xb = *(const float4*)&xT[kk][rl * 8 + 4];
      float4 wv = *(const float4*)&wlds[kk][cg * 4];
      float xr[8] = {xa.x, xa.y, xa.z, xa.w, xb.x, xb.y, xb.z, xb.w};
      float wc[4] = {wv.x, wv.y, wv.z, wv.w};
#pragma unroll
      for (int i = 0; i < 8; ++i)
#pragma unroll
        for (int j = 0; j < 4; ++j)
          acc[i][j] = fmaf(xr[i], wc[j], acc[i][j]);
    }
  }
#pragma unroll
  for (int i = 0; i < 8; ++i) {
    int r = rowbase + rl * 8 + i;
    if (r >= Nrows) continue;
    stnt_u2(outG + (size_t)r * 64 + cg * 2,
            pack_bf2(acc[i][0], acc[i][1]), pack_bf2(acc[i][2], acc[i][3]));
  }
}

// ---------------- pack W3|W4 into MFMA B-fragment order, split hi/lo ----------------
__global__ __launch_bounds__(256) void pack_w_kernel(
    const float* __restrict__ W3, const float* __restrict__ W4,
    ushort_t* __restrict__ Bhi, ushort_t* __restrict__ Blo) {
  int u = blockIdx.x * 256 + threadIdx.x;  // 0..2047 (grid = 8 blocks)
  int l = u & 63, kk = (u >> 6) & 3, t = u >> 8;
  int q = l >> 4, c = l & 15;
  int n = t * 16 + c;
  short8_t vh, vl;
#pragma unroll
  for (int j = 0; j < 8; ++j) {
    int k = kk * 32 + q * 8 + j;
    float w = (n < 64) ? W3[(size_t)k * 64 + n] : W4[(size_t)k * 64 + (n - 64)];
    uint_t hb = f2bf_bits(w);
    float wl = w - __builtin_bit_cast(float, hb << 16);
    vh[j] = (short)hb;
    vl[j] = (short)f2bf_bits(wl);
  }
  *(short8_t*)(Bhi + (size_t)u * 8) = vh;
  *(short8_t*)(Blo + (size_t)u * 8) = vl;
}

// ---------------- GEMM2 (MFMA): mean/std(fp32) = Xbf @ (Whi + Wlo) + [b3|b4] ----------------
__global__ __launch_bounds__(256) void gemm2_mfma_kernel(
    const ushort_t* __restrict__ Xbf, const ushort_t* __restrict__ Bhi,
    const ushort_t* __restrict__ Blo, const float* __restrict__ b3,
    const float* __restrict__ b4, float* __restrict__ outM,
    float* __restrict__ outS, int Nrows) {
  const int tid = threadIdx.x;
  const int wid = tid >> 6;
  const int lane = tid & 63;
  const int q = lane >> 4;
  const int c = lane & 15;
  const int rowbase = blockIdx.x * 64 + wid * 16;

  f32x4_t acc[8];
#pragma unroll
  for (int t = 0; t < 8; ++t) acc[t] = (f32x4_t){0.f, 0.f, 0.f, 0.f};

  int arow = rowbase + c;
  int ars = (arow < Nrows) ? arow : (Nrows - 1);
  const ushort_t* abase = Xbf + (size_t)ars * 128 + q * 8;

#pragma unroll
  for (int kk = 0; kk < 4; ++kk) {
    short8_t a = __builtin_nontemporal_load((const short8_t*)(abase + kk * 32));
#pragma unroll
    for (int t = 0; t < 8; ++t) {
      const size_t fo = ((size_t)(t * 4 + kk) * 64 + lane) * 8;
      short8_t bh = *(const short8_t*)(Bhi + fo);
      short8_t bl = *(const short8_t*)(Blo + fo);
      acc[t] = __builtin_amdgcn_mfma_f32_16x16x32_bf16(a, bh, acc[t], 0, 0, 0);
      acc[t] = __builtin_amdgcn_mfma_f32_16x16x32_bf16(a, bl, acc[t], 0, 0, 0);
    }
  }

#pragma unroll
  for (int t = 0; t < 8; ++t) {
    float bias = (t < 4) ? b3[t * 16 + c] : b4[(t - 4) * 16 + c];
    float* obase = (t < 4) ? (outM + t * 16 + c) : (outS + (t - 4) * 16 + c);
#pragma unroll
    for (int rr = 0; rr < 4; ++rr) {
      int row = rowbase + q * 4 + rr;
      if (row < Nrows)
        __builtin_nontemporal_store(acc[t][rr] + bias, obase + (size_t)row * 64);
    }
  }
}

// ---------------- gather aggregation: pair-gather (bf16 in/out, fp32 accum) ----------------
template<int EPI, bool SRCDV, typename IdxT>
__global__ __launch_bounds__(256) void aggregate_kernel(
    const uint_t* __restrict__ g, const int* __restrict__ deg,
    const IdxT* __restrict__ edge, const float* __restrict__ b1,
    uint_t* __restrict__ out, int Nn) {
  const int wave = threadIdx.x >> 6;
  const int lane = threadIdx.x & 63;
  const int n = blockIdx.x * 4 + wave;
  if (n >= Nn) return;
  const int dn = deg[n];
  const int cnt = (dn > 63) ? 63 : dn;
  const float sc = rsqrtf((float)(dn + 1));

  int vl = n;
  if (lane >= 1 && lane <= cnt) vl = (int)edge[(size_t)n * MAXDEG + (lane - 1)];
  float wl = 0.f;
  if (lane == 0)        wl = SRCDV ? sc : 1.f;
  else if (lane <= cnt) wl = SRCDV ? rsqrtf((float)(deg[vl] + 1)) : 1.f;

  const int h = lane >> 5;
  const int c = lane & 31;
  const uint_t* gc = g + c * 2;

  float a0 = 0.f, a1 = 0.f, a2 = 0.f, a3 = 0.f;
  const int entries = cnt + 1;
  const int npairs = (entries + 1) >> 1;

  int p = 0;
  for (; p + 4 <= npairs; p += 4) {
    int ss[4]; float ww[4]; uint2 uu[4];
#pragma unroll
    for (int t = 0; t < 4; ++t) {
      int j = 2 * (p + t) + h;
      ss[t] = __shfl(vl, j);
      ww[t] = __shfl(wl, j);
    }
#pragma unroll
    for (int t = 0; t < 4; ++t)
      uu[t] = *(const uint2*)(gc + (size_t)ss[t] * 64);
#pragma unroll
    for (int t = 0; t < 4; ++t) {
      a0 = fmaf(ww[t], bf_lo(uu[t].x), a0);
      a1 = fmaf(ww[t], bf_hi(uu[t].x), a1);
      a2 = fmaf(ww[t], bf_lo(uu[t].y), a2);
      a3 = fmaf(ww[t], bf_hi(uu[t].y), a3);
    }
  }
  for (; p < npairs; ++p) {
    int j = 2 * p + h;
    int s0 = __shfl(vl, j);
    float w0 = __shfl(wl, j);
    uint2 u = *(const uint2*)(gc + (size_t)s0 * 64);
    a0 = fmaf(w0, bf_lo(u.x), a0);
    a1 = fmaf(w0, bf_hi(u.x), a1);
    a2 = fmaf(w0, bf_lo(u.y), a2);
    a3 = fmaf(w0, bf_hi(u.y), a3);
  }

  a0 += __shfl_xor(a0, 32);
  a1 += __shfl_xor(a1, 32);
  a2 += __shfl_xor(a2, 32);
  a3 += __shfl_xor(a3, 32);

  if (h == 0) {
    if (EPI == 1) {
      float4 b = ((const float4*)b1)[c];
      a0 = fmaxf(fmaf(sc, a0, b.x), 0.f) * sc;
      a1 = fmaxf(fmaf(sc, a1, b.y), 0.f) * sc;
      a2 = fmaxf(fmaf(sc, a2, b.z), 0.f) * sc;
      a3 = fmaxf(fmaf(sc, a3, b.w), 0.f) * sc;
    } else {
      a0 *= sc; a1 *= sc; a2 *= sc; a3 *= sc;
    }
    stnt_u2(out + (size_t)n * 64 + c * 2, pack_bf2(a0, a1), pack_bf2(a2, a3));
  }
}

// ---------------- launch ----------------
extern "C" void kernel_launch(void* const* d_in, const int* in_sizes, int n_in,
                              void* d_out, int out_size, void* d_ws, size_t ws_size,
                              hipStream_t stream) {
  const float* x  = (const float*)d_in[0];
  const int*   ei = (const int*)d_in[1];
  const float* W1 = (const float*)d_in[2];
  const float* b1 = (const float*)d_in[3];
  const float* W3 = (const float*)d_in[4];
  const float* b3 = (const float*)d_in[5];
  const float* W4 = (const float*)d_in[6];
  const float* b4 = (const float*)d_in[7];

  const int N = in_sizes[0] / 128;
  const int E = in_sizes[1] / 2;
  const int* src = ei;
  const int* dst = ei + E;
  const bool small = (N <= 65535);
  const size_t esz = small ? sizeof(ushort_t) : sizeof(int);

  // coarse buckets: ranges of (1<<shift) nodes, at most 64 buckets
  int shift = 10;
  while (((N + (1 << shift) - 1) >> shift) > 64) ++shift;
  const int NB = (N + (1 << shift) - 1) >> shift;
  const int C = (E / NB) * 3 / 2 + 1024;  // per-bucket capacity, ~1.5x mean + slack

  char* w = (char*)d_ws;
  size_t off = 0;
  auto carve = [&](size_t bytes) { void* p = w + off; off = align256(off + bytes); return p; };
  int*      deg       = (int*)carve((size_t)N * sizeof(int));
  int*      bucketcnt = (int*)carve(64 * sizeof(int));
  uint2*    buckets   = (uint2*)carve((size_t)NB * C * sizeof(uint2));
  void*     edge      = carve((size_t)N * MAXDEG * esz);
  uint_t*   bufG      = (uint_t*)carve((size_t)N * 64 * sizeof(uint_t));  // [N,128] bf16
  uint_t*   bufH      = (uint_t*)carve((size_t)N * 64 * sizeof(uint_t));
  ushort_t* Bhi       = (ushort_t*)carve((size_t)16384 * sizeof(ushort_t));
  ushort_t* Blo       = (ushort_t*)carve((size_t)16384 * sizeof(ushort_t));

  float* out_mean = (float*)d_out;
  float* out_std  = out_mean + (size_t)N * 64;

  hipMemsetAsync(bucketcnt, 0, 64 * sizeof(int), stream);

  const int gblocks = (N + 63) / 64;
  const int ablocks = (N + 3) / 4;
  const int sblocks = (E + 2047) / 2048;

  pack_w_kernel<<<8, 256, 0, stream>>>(W3, W4, Bhi, Blo);
  bucket_scatter_kernel<<<sblocks, 256, 0, stream>>>(src, dst, buckets, bucketcnt, E, C, shift);

  if (small) {
    ushort_t* es = (ushort_t*)edge;
    bucket_to_rows_kernel<ushort_t, 1024><<<NB, 256, 0, stream>>>(
        buckets, bucketcnt, es, deg, N, C, shift);
    gemm1_kernel<<<gblocks, 256, 0, stream>>>(x, W1, bufG, N);
    aggregate_kernel<1, true,  ushort_t><<<ablocks, 256, 0, stream>>>(bufG, deg, es, b1, bufH, N);
    aggregate_kernel<2, false, ushort_t><<<ablocks, 256, 0, stream>>>(bufH, deg, es, nullptr, bufG, N);
  } else {
    int* es = (int*)edge;
    bucket_to_rows_kernel<int, 512><<<NB, 256, 0, stream>>>(
        buckets, bucketcnt, es, deg, N, C, shift);
    gemm1_kernel<<<gblocks, 256, 0, stream>>>(x, W1, bufG, N);
    aggregate_kernel<1, true,  int><<<ablocks, 256, 0, stream>>>(bufG, deg, es, b1, bufH, N);
    aggregate_kernel<2, false, int><<<ablocks, 256, 0, stream>>>(bufH, deg, es, nullptr, bufG, N);
  }
  gemm2_mfma_kernel<<<gblocks, 256, 0, stream>>>(
      (const ushort_t*)bufG, Bhi, Blo, b3, b4, out_mean, out_std, N);
}

// Round 8
// 145.610 us; speedup vs baseline: 1.2194x; 1.2194x over previous
//
#include <hip/hip_runtime.h>

typedef unsigned int uint_t;
typedef unsigned short ushort_t;

constexpr int MAXDEG = 64;   // slots per node row; deg ~ Poisson(16): P(deg >= 64) ~ 3e-22
// R1: cacheline-padding cursor REGRESSED — same-line atomic contention is NOT the issue.
// R2: batching 4 atomics 114->73us — atomic LATENCY chain was ~40us.
// R3: vmcnt-overlap schedule: NULL — fill cost is memory-side THROUGHPUT.
// R4: XCD-sliced edge regions: NULL — the ~51MB write excess tracks the ATOMIC count
//     (800K x 64B fabric transactions each), not edge-store locality.
// R5: gemm2 -> bf16 MFMA split-W: WIN 175->167, absmax unchanged.
// R6: pair-gather aggs: ~5us win -> aggs are BW-bound (~435MB random 256B gathers) = roofline.
// R7: two-phase LDS-binned CSR build: Phase B ran at 1.7% occupancy (49 blocks of 132KB LDS,
//     16K-edge serial scans) = 43.8us REGRESSION. But: pure gemm1 <= 43us (vs 71.5 fused)
//     proves the build-concept right — it just needs parallelism.
// R8: shift=7 -> 128-node buckets, NB~391 blocks, 17KB LDS/block (8 blocks/CU), ~2K edges
//     per scan. Phase A hist grows to 512 counters (LDS, free); ~150K reservation atomics
//     (5x fewer than the original 800K per-edge).

// ---------------- bf16 helpers (RNE) ----------------
static __device__ __forceinline__ uint_t f2bf_bits(float f) {
  uint_t u = __builtin_bit_cast(uint_t, f);
  return (u + 0x7fffu + ((u >> 16) & 1u)) >> 16;
}
static __device__ __forceinline__ uint_t pack_bf2(float lo, float hi) {
  return f2bf_bits(lo) | (f2bf_bits(hi) << 16);
}
static __device__ __forceinline__ float bf_lo(uint_t u) {
  return __builtin_bit_cast(float, u << 16);
}
static __device__ __forceinline__ float bf_hi(uint_t u) {
  return __builtin_bit_cast(float, u & 0xffff0000u);
}

// ---------------- vector types ----------------
typedef __attribute__((ext_vector_type(2))) uint_t v2u;
typedef __attribute__((ext_vector_type(8))) short  short8_t;  // 8 bf16 (4 VGPRs)
typedef __attribute__((ext_vector_type(4))) float  f32x4_t;   // MFMA acc

static __device__ __forceinline__ void stnt_u2(uint_t* p, uint_t a, uint_t b) {
  v2u t; t.x = a; t.y = b;
  __builtin_nontemporal_store(t, (v2u*)p);
}

static inline size_t align256(size_t x) { return (x + 255) & ~(size_t)255; }

// ---------------- Phase A: bin edges into dst-range buckets (<=512) ----------------
// 2048 edges/block. LDS histogram, one global reservation atomic per non-empty bucket
// per block, then contiguous uint2 (dst,src) runs per bucket.
__global__ __launch_bounds__(256) void bucket_scatter_kernel(
    const int* __restrict__ src, const int* __restrict__ dst,
    uint2* __restrict__ buckets, int* __restrict__ bucketcnt,
    int E, int C, int shift, int NB) {
  __shared__ int hist[512];
  __shared__ int base[512];
  const int tid = threadIdx.x;
  const int e0 = blockIdx.x * 2048;

  for (int i = tid; i < NB; i += 256) hist[i] = 0;
  __syncthreads();

  int dd[8], ss[8], slot[8];
#pragma unroll
  for (int i = 0; i < 8; ++i) {
    int e = e0 + tid + i * 256;
    bool ok = (e < E);
    dd[i] = ok ? dst[e] : -1;
    ss[i] = ok ? src[e] : 0;
    slot[i] = ok ? atomicAdd(&hist[dd[i] >> shift], 1) : 0;
  }
  __syncthreads();

  for (int i = tid; i < NB; i += 256) {
    int c = hist[i];
    base[i] = (c > 0) ? atomicAdd(&bucketcnt[i], c) : 0;
  }
  __syncthreads();

#pragma unroll
  for (int i = 0; i < 8; ++i) {
    if (dd[i] < 0) continue;
    int b = dd[i] >> shift;
    int pos = base[b] + slot[i];
    if (pos < C)  // capacity guard (P ~ 0 with 1.5x margin)
      buckets[(size_t)b * C + pos] = make_uint2((uint_t)dd[i], (uint_t)ss[i]);
  }
}

// ---------------- Phase B: bucket -> 64-slot CSR rows + deg, all in LDS ----------------
// One block per bucket; WIN-node windows (WIN*MAXDEG IdxT rows in LDS).
template<typename IdxT, int WIN>
__global__ __launch_bounds__(256) void bucket_to_rows_kernel(
    const uint2* __restrict__ buckets, const int* __restrict__ bucketcnt,
    IdxT* __restrict__ edge, int* __restrict__ deg, int Nn, int C, int shift) {
  __shared__ __align__(16) IdxT rows[WIN * MAXDEG];
  __shared__ int cnt[WIN];
  const int tid = threadIdx.x;
  const int b = blockIdx.x;
  const int node0 = b << shift;
  const int RANGE = 1 << shift;
  int ec = bucketcnt[b];
  if (ec > C) ec = C;
  const uint2* bb = buckets + (size_t)b * C;

  for (int w0 = 0; w0 < RANGE; w0 += WIN) {
    for (int i = tid; i < WIN; i += 256) cnt[i] = 0;
    __syncthreads();
    for (int i = tid; i < ec; i += 256) {
      uint2 it = bb[i];
      int local = (int)it.x - node0 - w0;
      if (local >= 0 && local < WIN) {
        int sl = atomicAdd(&cnt[local], 1);
        if (sl < MAXDEG) rows[local * MAXDEG + sl] = (IdxT)it.y;
      }
    }
    __syncthreads();
    const int nbase = node0 + w0;
    constexpr int PER = (MAXDEG * sizeof(IdxT)) / 16;  // uint4 per node row
    const uint4* rv = (const uint4*)rows;
    uint4* ev = (uint4*)(edge + (size_t)nbase * MAXDEG);
    for (int i = tid; i < WIN * PER; i += 256) {
      int node = nbase + i / PER;
      if (node < Nn) ev[i] = rv[i];
    }
    for (int i = tid; i < WIN; i += 256) {
      int node = nbase + i;
      if (node < Nn) deg[node] = cnt[i];  // raw count (agg clamps)
    }
    __syncthreads();
  }
}

// ---------------- GEMM1 (pure): outG(bf16) = X @ W1 ----------------
__global__ __launch_bounds__(256) void gemm1_kernel(
    const float* __restrict__ X, const float* __restrict__ W1,
    uint_t* __restrict__ outG, int Nrows) {
  constexpr int BK = 64;
  __shared__ float wlds[BK][128];
  __shared__ float xT[BK][68];

  const int tid = threadIdx.x;
  const int cg = tid & 31;
  const int rl = tid >> 5;
  const int rowbase = blockIdx.x * 64;

  float acc[8][4];
#pragma unroll
  for (int i = 0; i < 8; ++i)
#pragma unroll
    for (int j = 0; j < 4; ++j) acc[i][j] = 0.f;

  for (int k0 = 0; k0 < 128; k0 += BK) {
    __syncthreads();
#pragma unroll
    for (int i = 0; i < 8; ++i) {
      int f = tid + i * 256;
      int kk = f >> 5, cc = f & 31;
      float4 v = ((const float4*)W1)[(size_t)(k0 + kk) * 32 + cc];
      *(float4*)&wlds[kk][cc * 4] = v;
    }
    {
      int r = tid >> 2;
      int rg = rowbase + r;
      int rs = (rg < Nrows) ? rg : (Nrows - 1);
      const float4* xrow = (const float4*)(X + (size_t)rs * 128);
      bool valid = (rg < Nrows);
#pragma unroll
      for (int p = 0; p < 4; ++p) {
        int kf4 = (tid & 3) + p * 4;
        float4 v = xrow[(k0 >> 2) + kf4];
        if (!valid) v = make_float4(0.f, 0.f, 0.f, 0.f);
        int ke = kf4 * 4;
        xT[ke + 0][r] = v.x;
        xT[ke + 1][r] = v.y;
        xT[ke + 2][r] = v.z;
        xT[ke + 3][r] = v.w;
      }
    }
    __syncthreads();
#pragma unroll 8
    for (int kk = 0; kk < BK; ++kk) {
      float4 xa = *(const float4*)&xT[kk][rl * 8];
      float4 xb = *(const float4*)&xT[kk][rl * 8 + 4];
      float4 wv = *(const float4*)&wlds[kk][cg * 4];
      float xr[8] = {xa.x, xa.y, xa.z, xa.w, xb.x, xb.y, xb.z, xb.w};
      float wc[4] = {wv.x, wv.y, wv.z, wv.w};
#pragma unroll
      for (int i = 0; i < 8; ++i)
#pragma unroll
        for (int j = 0; j < 4; ++j)
          acc[i][j] = fmaf(xr[i], wc[j], acc[i][j]);
    }
  }
#pragma unroll
  for (int i = 0; i < 8; ++i) {
    int r = rowbase + rl * 8 + i;
    if (r >= Nrows) continue;
    stnt_u2(outG + (size_t)r * 64 + cg * 2,
            pack_bf2(acc[i][0], acc[i][1]), pack_bf2(acc[i][2], acc[i][3]));
  }
}

// ---------------- pack W3|W4 into MFMA B-fragment order, split hi/lo ----------------
__global__ __launch_bounds__(256) void pack_w_kernel(
    const float* __restrict__ W3, const float* __restrict__ W4,
    ushort_t* __restrict__ Bhi, ushort_t* __restrict__ Blo) {
  int u = blockIdx.x * 256 + threadIdx.x;  // 0..2047 (grid = 8 blocks)
  int l = u & 63, kk = (u >> 6) & 3, t = u >> 8;
  int q = l >> 4, c = l & 15;
  int n = t * 16 + c;
  short8_t vh, vl;
#pragma unroll
  for (int j = 0; j < 8; ++j) {
    int k = kk * 32 + q * 8 + j;
    float w = (n < 64) ? W3[(size_t)k * 64 + n] : W4[(size_t)k * 64 + (n - 64)];
    uint_t hb = f2bf_bits(w);
    float wl = w - __builtin_bit_cast(float, hb << 16);
    vh[j] = (short)hb;
    vl[j] = (short)f2bf_bits(wl);
  }
  *(short8_t*)(Bhi + (size_t)u * 8) = vh;
  *(short8_t*)(Blo + (size_t)u * 8) = vl;
}

// ---------------- GEMM2 (MFMA): mean/std(fp32) = Xbf @ (Whi + Wlo) + [b3|b4] ----------------
__global__ __launch_bounds__(256) void gemm2_mfma_kernel(
    const ushort_t* __restrict__ Xbf, const ushort_t* __restrict__ Bhi,
    const ushort_t* __restrict__ Blo, const float* __restrict__ b3,
    const float* __restrict__ b4, float* __restrict__ outM,
    float* __restrict__ outS, int Nrows) {
  const int tid = threadIdx.x;
  const int wid = tid >> 6;
  const int lane = tid & 63;
  const int q = lane >> 4;
  const int c = lane & 15;
  const int rowbase = blockIdx.x * 64 + wid * 16;

  f32x4_t acc[8];
#pragma unroll
  for (int t = 0; t < 8; ++t) acc[t] = (f32x4_t){0.f, 0.f, 0.f, 0.f};

  int arow = rowbase + c;
  int ars = (arow < Nrows) ? arow : (Nrows - 1);
  const ushort_t* abase = Xbf + (size_t)ars * 128 + q * 8;

#pragma unroll
  for (int kk = 0; kk < 4; ++kk) {
    short8_t a = __builtin_nontemporal_load((const short8_t*)(abase + kk * 32));
#pragma unroll
    for (int t = 0; t < 8; ++t) {
      const size_t fo = ((size_t)(t * 4 + kk) * 64 + lane) * 8;
      short8_t bh = *(const short8_t*)(Bhi + fo);
      short8_t bl = *(const short8_t*)(Blo + fo);
      acc[t] = __builtin_amdgcn_mfma_f32_16x16x32_bf16(a, bh, acc[t], 0, 0, 0);
      acc[t] = __builtin_amdgcn_mfma_f32_16x16x32_bf16(a, bl, acc[t], 0, 0, 0);
    }
  }

#pragma unroll
  for (int t = 0; t < 8; ++t) {
    float bias = (t < 4) ? b3[t * 16 + c] : b4[(t - 4) * 16 + c];
    float* obase = (t < 4) ? (outM + t * 16 + c) : (outS + (t - 4) * 16 + c);
#pragma unroll
    for (int rr = 0; rr < 4; ++rr) {
      int row = rowbase + q * 4 + rr;
      if (row < Nrows)
        __builtin_nontemporal_store(acc[t][rr] + bias, obase + (size_t)row * 64);
    }
  }
}

// ---------------- gather aggregation: pair-gather (bf16 in/out, fp32 accum) ----------------
template<int EPI, bool SRCDV, typename IdxT>
__global__ __launch_bounds__(256) void aggregate_kernel(
    const uint_t* __restrict__ g, const int* __restrict__ deg,
    const IdxT* __restrict__ edge, const float* __restrict__ b1,
    uint_t* __restrict__ out, int Nn) {
  const int wave = threadIdx.x >> 6;
  const int lane = threadIdx.x & 63;
  const int n = blockIdx.x * 4 + wave;
  if (n >= Nn) return;
  const int dn = deg[n];
  const int cnt = (dn > 63) ? 63 : dn;
  const float sc = rsqrtf((float)(dn + 1));

  int vl = n;
  if (lane >= 1 && lane <= cnt) vl = (int)edge[(size_t)n * MAXDEG + (lane - 1)];
  float wl = 0.f;
  if (lane == 0)        wl = SRCDV ? sc : 1.f;
  else if (lane <= cnt) wl = SRCDV ? rsqrtf((float)(deg[vl] + 1)) : 1.f;

  const int h = lane >> 5;
  const int c = lane & 31;
  const uint_t* gc = g + c * 2;

  float a0 = 0.f, a1 = 0.f, a2 = 0.f, a3 = 0.f;
  const int entries = cnt + 1;
  const int npairs = (entries + 1) >> 1;

  int p = 0;
  for (; p + 4 <= npairs; p += 4) {
    int ss[4]; float ww[4]; uint2 uu[4];
#pragma unroll
    for (int t = 0; t < 4; ++t) {
      int j = 2 * (p + t) + h;
      ss[t] = __shfl(vl, j);
      ww[t] = __shfl(wl, j);
    }
#pragma unroll
    for (int t = 0; t < 4; ++t)
      uu[t] = *(const uint2*)(gc + (size_t)ss[t] * 64);
#pragma unroll
    for (int t = 0; t < 4; ++t) {
      a0 = fmaf(ww[t], bf_lo(uu[t].x), a0);
      a1 = fmaf(ww[t], bf_hi(uu[t].x), a1);
      a2 = fmaf(ww[t], bf_lo(uu[t].y), a2);
      a3 = fmaf(ww[t], bf_hi(uu[t].y), a3);
    }
  }
  for (; p < npairs; ++p) {
    int j = 2 * p + h;
    int s0 = __shfl(vl, j);
    float w0 = __shfl(wl, j);
    uint2 u = *(const uint2*)(gc + (size_t)s0 * 64);
    a0 = fmaf(w0, bf_lo(u.x), a0);
    a1 = fmaf(w0, bf_hi(u.x), a1);
    a2 = fmaf(w0, bf_lo(u.y), a2);
    a3 = fmaf(w0, bf_hi(u.y), a3);
  }

  a0 += __shfl_xor(a0, 32);
  a1 += __shfl_xor(a1, 32);
  a2 += __shfl_xor(a2, 32);
  a3 += __shfl_xor(a3, 32);

  if (h == 0) {
    if (EPI == 1) {
      float4 b = ((const float4*)b1)[c];
      a0 = fmaxf(fmaf(sc, a0, b.x), 0.f) * sc;
      a1 = fmaxf(fmaf(sc, a1, b.y), 0.f) * sc;
      a2 = fmaxf(fmaf(sc, a2, b.z), 0.f) * sc;
      a3 = fmaxf(fmaf(sc, a3, b.w), 0.f) * sc;
    } else {
      a0 *= sc; a1 *= sc; a2 *= sc; a3 *= sc;
    }
    stnt_u2(out + (size_t)n * 64 + c * 2, pack_bf2(a0, a1), pack_bf2(a2, a3));
  }
}

// ---------------- launch ----------------
extern "C" void kernel_launch(void* const* d_in, const int* in_sizes, int n_in,
                              void* d_out, int out_size, void* d_ws, size_t ws_size,
                              hipStream_t stream) {
  const float* x  = (const float*)d_in[0];
  const int*   ei = (const int*)d_in[1];
  const float* W1 = (const float*)d_in[2];
  const float* b1 = (const float*)d_in[3];
  const float* W3 = (const float*)d_in[4];
  const float* b3 = (const float*)d_in[5];
  const float* W4 = (const float*)d_in[6];
  const float* b4 = (const float*)d_in[7];

  const int N = in_sizes[0] / 128;
  const int E = in_sizes[1] / 2;
  const int* src = ei;
  const int* dst = ei + E;
  const bool small = (N <= 65535);
  const size_t esz = small ? sizeof(ushort_t) : sizeof(int);

  // buckets: ranges of (1<<shift) nodes, at most 512 buckets (LDS histogram size)
  int shift = 7;
  while (((N + (1 << shift) - 1) >> shift) > 512) ++shift;
  const int NB = (N + (1 << shift) - 1) >> shift;
  const int C = (E / NB) * 3 / 2 + 512;  // per-bucket capacity, ~1.5x mean + slack

  char* w = (char*)d_ws;
  size_t off = 0;
  auto carve = [&](size_t bytes) { void* p = w + off; off = align256(off + bytes); return p; };
  int*      deg       = (int*)carve((size_t)N * sizeof(int));
  int*      bucketcnt = (int*)carve(512 * sizeof(int));
  uint2*    buckets   = (uint2*)carve((size_t)NB * C * sizeof(uint2));
  void*     edge      = carve((size_t)N * MAXDEG * esz);
  uint_t*   bufG      = (uint_t*)carve((size_t)N * 64 * sizeof(uint_t));  // [N,128] bf16
  uint_t*   bufH      = (uint_t*)carve((size_t)N * 64 * sizeof(uint_t));
  ushort_t* Bhi       = (ushort_t*)carve((size_t)16384 * sizeof(ushort_t));
  ushort_t* Blo       = (ushort_t*)carve((size_t)16384 * sizeof(ushort_t));

  float* out_mean = (float*)d_out;
  float* out_std  = out_mean + (size_t)N * 64;

  hipMemsetAsync(bucketcnt, 0, 512 * sizeof(int), stream);

  const int gblocks = (N + 63) / 64;
  const int ablocks = (N + 3) / 4;
  const int sblocks = (E + 2047) / 2048;

  pack_w_kernel<<<8, 256, 0, stream>>>(W3, W4, Bhi, Blo);
  bucket_scatter_kernel<<<sblocks, 256, 0, stream>>>(src, dst, buckets, bucketcnt, E, C, shift, NB);

  if (small) {
    ushort_t* es = (ushort_t*)edge;
    bucket_to_rows_kernel<ushort_t, 128><<<NB, 256, 0, stream>>>(
        buckets, bucketcnt, es, deg, N, C, shift);
    gemm1_kernel<<<gblocks, 256, 0, stream>>>(x, W1, bufG, N);
    aggregate_kernel<1, true,  ushort_t><<<ablocks, 256, 0, stream>>>(bufG, deg, es, b1, bufH, N);
    aggregate_kernel<2, false, ushort_t><<<ablocks, 256, 0, stream>>>(bufH, deg, es, nullptr, bufG, N);
  } else {
    int* es = (int*)edge;
    bucket_to_rows_kernel<int, 128><<<NB, 256, 0, stream>>>(
        buckets, bucketcnt, es, deg, N, C, shift);
    gemm1_kernel<<<gblocks, 256, 0, stream>>>(x, W1, bufG, N);
    aggregate_kernel<1, true,  int><<<ablocks, 256, 0, stream>>>(bufG, deg, es, b1, bufH, N);
    aggregate_kernel<2, false, int><<<ablocks, 256, 0, stream>>>(bufH, deg, es, nullptr, bufG, N);
  }
  gemm2_mfma_kernel<<<gblocks, 256, 0, stream>>>(
      (const ushort_t*)bufG, Bhi, Blo, b3, b4, out_mean, out_std, N);
}

// Round 10
// 126.242 us; speedup vs baseline: 1.4065x; 1.1534x over previous
//
#include <hip/hip_runtime.h>

typedef unsigned int uint_t;
typedef unsigned short ushort_t;

constexpr int MAXDEG = 64;   // slots per node row; deg ~ Poisson(16): P(deg >= 64) ~ 3e-22
// R1: cacheline-padding cursor REGRESSED — same-line atomic contention is NOT the issue.
// R2: batching 4 atomics 114->73us — atomic LATENCY chain was ~40us.
// R3: vmcnt-overlap schedule: NULL — fill cost is memory-side THROUGHPUT.
// R4: XCD-sliced edge regions: NULL — write excess tracks the ATOMIC count (64B/atomic).
// R5: gemm2 -> bf16 MFMA split-W (Whi+Wlo, fp32 acc): WIN 175->167, absmax unchanged.
// R6: pair-gather aggs: ~5us win -> aggs BW-bound (~435MB random 256B gathers from L3) = roofline.
// R7: LDS-binned CSR build at 49 blocks = 1.7% occupancy: 43.8us. Concept right, no parallelism.
// R8: shift=7 (128-node buckets, ~391 blocks): WIN 177->145.6. Build ~8us total.
// R9: gemm1 -> MFMA, both operands split: CRASHED — bucketcnt zeroing in pack_w block 0 only
//     covered [0..255] (blockDim=256, "tid<512" was vacuous); buckets 256+ got garbage bases,
//     negative pos => OOB write => heap corruption. MFMA theory never tested.
// R10: fix: each thread zeroes 2 entries; sign guards on pos/ec. Identical otherwise.

// ---------------- bf16 helpers (RNE) ----------------
static __device__ __forceinline__ uint_t f2bf_bits(float f) {
  uint_t u = __builtin_bit_cast(uint_t, f);
  return (u + 0x7fffu + ((u >> 16) & 1u)) >> 16;
}
static __device__ __forceinline__ uint_t pack_bf2(float lo, float hi) {
  return f2bf_bits(lo) | (f2bf_bits(hi) << 16);
}
static __device__ __forceinline__ float bf_lo(uint_t u) {
  return __builtin_bit_cast(float, u << 16);
}
static __device__ __forceinline__ float bf_hi(uint_t u) {
  return __builtin_bit_cast(float, u & 0xffff0000u);
}

// ---------------- vector types ----------------
typedef __attribute__((ext_vector_type(2))) uint_t v2u;
typedef __attribute__((ext_vector_type(8))) short  short8_t;  // 8 bf16 (4 VGPRs)
typedef __attribute__((ext_vector_type(4))) float  f32x4_t;   // MFMA acc

static __device__ __forceinline__ void stnt_u2(uint_t* p, uint_t a, uint_t b) {
  v2u t; t.x = a; t.y = b;
  __builtin_nontemporal_store(t, (v2u*)p);
}

static inline size_t align256(size_t x) { return (x + 255) & ~(size_t)255; }

// ---------------- Phase A: bin edges into dst-range buckets (<=512) ----------------
__global__ __launch_bounds__(256) void bucket_scatter_kernel(
    const int* __restrict__ src, const int* __restrict__ dst,
    uint2* __restrict__ buckets, int* __restrict__ bucketcnt,
    int E, int C, int shift, int NB) {
  __shared__ int hist[512];
  __shared__ int base[512];
  const int tid = threadIdx.x;
  const int e0 = blockIdx.x * 2048;

  for (int i = tid; i < NB; i += 256) hist[i] = 0;
  __syncthreads();

  int dd[8], ss[8], slot[8];
#pragma unroll
  for (int i = 0; i < 8; ++i) {
    int e = e0 + tid + i * 256;
    bool ok = (e < E);
    dd[i] = ok ? dst[e] : -1;
    ss[i] = ok ? src[e] : 0;
    slot[i] = ok ? atomicAdd(&hist[dd[i] >> shift], 1) : 0;
  }
  __syncthreads();

  for (int i = tid; i < NB; i += 256) {
    int c = hist[i];
    base[i] = (c > 0) ? atomicAdd(&bucketcnt[i], c) : 0;
  }
  __syncthreads();

#pragma unroll
  for (int i = 0; i < 8; ++i) {
    if (dd[i] < 0) continue;
    int b = dd[i] >> shift;
    int pos = base[b] + slot[i];
    if (pos >= 0 && pos < C)  // capacity + sign guard
      buckets[(size_t)b * C + pos] = make_uint2((uint_t)dd[i], (uint_t)ss[i]);
  }
}

// ---------------- Phase B: bucket -> 64-slot CSR rows + deg, all in LDS ----------------
template<typename IdxT, int WIN>
__global__ __launch_bounds__(256) void bucket_to_rows_kernel(
    const uint2* __restrict__ buckets, const int* __restrict__ bucketcnt,
    IdxT* __restrict__ edge, int* __restrict__ deg, int Nn, int C, int shift) {
  __shared__ __align__(16) IdxT rows[WIN * MAXDEG];
  __shared__ int cnt[WIN];
  const int tid = threadIdx.x;
  const int b = blockIdx.x;
  const int node0 = b << shift;
  const int RANGE = 1 << shift;
  int ec = bucketcnt[b];
  if (ec > C) ec = C;
  if (ec < 0) ec = 0;
  const uint2* bb = buckets + (size_t)b * C;

  for (int w0 = 0; w0 < RANGE; w0 += WIN) {
    for (int i = tid; i < WIN; i += 256) cnt[i] = 0;
    __syncthreads();
    for (int i = tid; i < ec; i += 256) {
      uint2 it = bb[i];
      int local = (int)it.x - node0 - w0;
      if (local >= 0 && local < WIN) {
        int sl = atomicAdd(&cnt[local], 1);
        if (sl < MAXDEG) rows[local * MAXDEG + sl] = (IdxT)it.y;
      }
    }
    __syncthreads();
    const int nbase = node0 + w0;
    constexpr int PER = (MAXDEG * sizeof(IdxT)) / 16;  // uint4 per node row
    const uint4* rv = (const uint4*)rows;
    uint4* ev = (uint4*)(edge + (size_t)nbase * MAXDEG);
    for (int i = tid; i < WIN * PER; i += 256) {
      int node = nbase + i / PER;
      if (node < Nn) ev[i] = rv[i];
    }
    for (int i = tid; i < WIN; i += 256) {
      int node = nbase + i;
      if (node < Nn) deg[node] = cnt[i];  // raw count (agg clamps)
    }
    __syncthreads();
  }
}

// ---------------- pack weights into MFMA B-fragment order, split hi/lo ----------------
// Blocks 0-7:  W1 (128x128)       -> B1hi/B1lo
// Blocks 8-15: [W3|W4] (128x128)  -> B2hi/B2lo
// Block 0 also zeroes bucketcnt[512] (2 entries/thread; runs before bucket_scatter).
__global__ __launch_bounds__(256) void pack_w_kernel(
    const float* __restrict__ W1, const float* __restrict__ W3,
    const float* __restrict__ W4,
    ushort_t* __restrict__ B1hi, ushort_t* __restrict__ B1lo,
    ushort_t* __restrict__ B2hi, ushort_t* __restrict__ B2lo,
    int* __restrict__ bucketcnt) {
  if (blockIdx.x == 0) {
    bucketcnt[threadIdx.x] = 0;
    bucketcnt[threadIdx.x + 256] = 0;
  }
  const bool w1 = (blockIdx.x < 8);
  int u = (w1 ? blockIdx.x : blockIdx.x - 8) * 256 + threadIdx.x;  // 0..2047
  int l = u & 63, kk = (u >> 6) & 3, t = u >> 8;
  int q = l >> 4, c = l & 15;
  int n = t * 16 + c;
  short8_t vh, vl;
#pragma unroll
  for (int j = 0; j < 8; ++j) {
    int k = kk * 32 + q * 8 + j;
    float w;
    if (w1)          w = W1[(size_t)k * 128 + n];
    else if (n < 64) w = W3[(size_t)k * 64 + n];
    else             w = W4[(size_t)k * 64 + (n - 64)];
    uint_t hb = f2bf_bits(w);
    float wl = w - __builtin_bit_cast(float, hb << 16);
    vh[j] = (short)hb;
    vl[j] = (short)f2bf_bits(wl);
  }
  ushort_t* ph = w1 ? B1hi : B2hi;
  ushort_t* pl = w1 ? B1lo : B2lo;
  *(short8_t*)(ph + (size_t)u * 8) = vh;
  *(short8_t*)(pl + (size_t)u * 8) = vl;
}

// ---------------- GEMM1 (MFMA): outG(bf16) = X @ W1, both operands hi/lo-split ----------------
// A: X fp32 rows converted in-register to Xhi+Xlo bf16 fragments.
// 3 MFMAs/tile: Xhi*Whi + Xhi*Wlo + Xlo*Whi (Xlo*Wlo ~ 2^-18 rel, dropped; output is bf16).
__global__ __launch_bounds__(256) void gemm1_mfma_kernel(
    const float* __restrict__ X, const ushort_t* __restrict__ Bhi,
    const ushort_t* __restrict__ Blo, ushort_t* __restrict__ outG, int Nrows) {
  const int tid = threadIdx.x;
  const int wid = tid >> 6;
  const int lane = tid & 63;
  const int q = lane >> 4;
  const int c = lane & 15;
  const int rowbase = blockIdx.x * 64 + wid * 16;

  f32x4_t acc[8];
#pragma unroll
  for (int t = 0; t < 8; ++t) acc[t] = (f32x4_t){0.f, 0.f, 0.f, 0.f};

  int arow = rowbase + c;
  int ars = (arow < Nrows) ? arow : (Nrows - 1);
  const float* abase = X + (size_t)ars * 128 + q * 8;

#pragma unroll
  for (int kk = 0; kk < 4; ++kk) {
    float4 xa = *(const float4*)(abase + kk * 32);
    float4 xb = *(const float4*)(abase + kk * 32 + 4);
    float xf[8] = {xa.x, xa.y, xa.z, xa.w, xb.x, xb.y, xb.z, xb.w};
    short8_t ahi, alo;
#pragma unroll
    for (int j = 0; j < 8; ++j) {
      float f = xf[j];
      uint_t hb = f2bf_bits(f);
      ahi[j] = (short)hb;
      float fl = f - __builtin_bit_cast(float, hb << 16);
      alo[j] = (short)f2bf_bits(fl);
    }
#pragma unroll
    for (int t = 0; t < 8; ++t) {
      const size_t fo = ((size_t)(t * 4 + kk) * 64 + lane) * 8;
      short8_t bh = *(const short8_t*)(Bhi + fo);
      short8_t bl = *(const short8_t*)(Blo + fo);
      acc[t] = __builtin_amdgcn_mfma_f32_16x16x32_bf16(ahi, bh, acc[t], 0, 0, 0);
      acc[t] = __builtin_amdgcn_mfma_f32_16x16x32_bf16(ahi, bl, acc[t], 0, 0, 0);
      acc[t] = __builtin_amdgcn_mfma_f32_16x16x32_bf16(alo, bh, acc[t], 0, 0, 0);
    }
  }

  // C/D: col = t*16 + c, row = rowbase + q*4 + rr; bf16 element stores
#pragma unroll
  for (int t = 0; t < 8; ++t) {
#pragma unroll
    for (int rr = 0; rr < 4; ++rr) {
      int row = rowbase + q * 4 + rr;
      if (row < Nrows)
        outG[(size_t)row * 128 + t * 16 + c] = (ushort_t)f2bf_bits(acc[t][rr]);
    }
  }
}

// ---------------- GEMM2 (MFMA): mean/std(fp32) = Xbf @ (Whi + Wlo) + [b3|b4] ----------------
__global__ __launch_bounds__(256) void gemm2_mfma_kernel(
    const ushort_t* __restrict__ Xbf, const ushort_t* __restrict__ Bhi,
    const ushort_t* __restrict__ Blo, const float* __restrict__ b3,
    const float* __restrict__ b4, float* __restrict__ outM,
    float* __restrict__ outS, int Nrows) {
  const int tid = threadIdx.x;
  const int wid = tid >> 6;
  const int lane = tid & 63;
  const int q = lane >> 4;
  const int c = lane & 15;
  const int rowbase = blockIdx.x * 64 + wid * 16;

  f32x4_t acc[8];
#pragma unroll
  for (int t = 0; t < 8; ++t) acc[t] = (f32x4_t){0.f, 0.f, 0.f, 0.f};

  int arow = rowbase + c;
  int ars = (arow < Nrows) ? arow : (Nrows - 1);
  const ushort_t* abase = Xbf + (size_t)ars * 128 + q * 8;

#pragma unroll
  for (int kk = 0; kk < 4; ++kk) {
    short8_t a = __builtin_nontemporal_load((const short8_t*)(abase + kk * 32));
#pragma unroll
    for (int t = 0; t < 8; ++t) {
      const size_t fo = ((size_t)(t * 4 + kk) * 64 + lane) * 8;
      short8_t bh = *(const short8_t*)(Bhi + fo);
      short8_t bl = *(const short8_t*)(Blo + fo);
      acc[t] = __builtin_amdgcn_mfma_f32_16x16x32_bf16(a, bh, acc[t], 0, 0, 0);
      acc[t] = __builtin_amdgcn_mfma_f32_16x16x32_bf16(a, bl, acc[t], 0, 0, 0);
    }
  }

#pragma unroll
  for (int t = 0; t < 8; ++t) {
    float bias = (t < 4) ? b3[t * 16 + c] : b4[(t - 4) * 16 + c];
    float* obase = (t < 4) ? (outM + t * 16 + c) : (outS + (t - 4) * 16 + c);
#pragma unroll
    for (int rr = 0; rr < 4; ++rr) {
      int row = rowbase + q * 4 + rr;
      if (row < Nrows)
        __builtin_nontemporal_store(acc[t][rr] + bias, obase + (size_t)row * 64);
    }
  }
}

// ---------------- gather aggregation: pair-gather (bf16 in/out, fp32 accum) ----------------
template<int EPI, bool SRCDV, typename IdxT>
__global__ __launch_bounds__(256) void aggregate_kernel(
    const uint_t* __restrict__ g, const int* __restrict__ deg,
    const IdxT* __restrict__ edge, const float* __restrict__ b1,
    uint_t* __restrict__ out, int Nn) {
  const int wave = threadIdx.x >> 6;
  const int lane = threadIdx.x & 63;
  const int n = blockIdx.x * 4 + wave;
  if (n >= Nn) return;
  const int dn = deg[n];
  const int cnt = (dn > 63) ? 63 : dn;
  const float sc = rsqrtf((float)(dn + 1));

  int vl = n;
  if (lane >= 1 && lane <= cnt) vl = (int)edge[(size_t)n * MAXDEG + (lane - 1)];
  float wl = 0.f;
  if (lane == 0)        wl = SRCDV ? sc : 1.f;
  else if (lane <= cnt) wl = SRCDV ? rsqrtf((float)(deg[vl] + 1)) : 1.f;

  const int h = lane >> 5;
  const int c = lane & 31;
  const uint_t* gc = g + c * 2;

  float a0 = 0.f, a1 = 0.f, a2 = 0.f, a3 = 0.f;
  const int entries = cnt + 1;
  const int npairs = (entries + 1) >> 1;

  int p = 0;
  for (; p + 4 <= npairs; p += 4) {
    int ss[4]; float ww[4]; uint2 uu[4];
#pragma unroll
    for (int t = 0; t < 4; ++t) {
      int j = 2 * (p + t) + h;
      ss[t] = __shfl(vl, j);
      ww[t] = __shfl(wl, j);
    }
#pragma unroll
    for (int t = 0; t < 4; ++t)
      uu[t] = *(const uint2*)(gc + (size_t)ss[t] * 64);
#pragma unroll
    for (int t = 0; t < 4; ++t) {
      a0 = fmaf(ww[t], bf_lo(uu[t].x), a0);
      a1 = fmaf(ww[t], bf_hi(uu[t].x), a1);
      a2 = fmaf(ww[t], bf_lo(uu[t].y), a2);
      a3 = fmaf(ww[t], bf_hi(uu[t].y), a3);
    }
  }
  for (; p < npairs; ++p) {
    int j = 2 * p + h;
    int s0 = __shfl(vl, j);
    float w0 = __shfl(wl, j);
    uint2 u = *(const uint2*)(gc + (size_t)s0 * 64);
    a0 = fmaf(w0, bf_lo(u.x), a0);
    a1 = fmaf(w0, bf_hi(u.x), a1);
    a2 = fmaf(w0, bf_lo(u.y), a2);
    a3 = fmaf(w0, bf_hi(u.y), a3);
  }

  a0 += __shfl_xor(a0, 32);
  a1 += __shfl_xor(a1, 32);
  a2 += __shfl_xor(a2, 32);
  a3 += __shfl_xor(a3, 32);

  if (h == 0) {
    if (EPI == 1) {
      float4 b = ((const float4*)b1)[c];
      a0 = fmaxf(fmaf(sc, a0, b.x), 0.f) * sc;
      a1 = fmaxf(fmaf(sc, a1, b.y), 0.f) * sc;
      a2 = fmaxf(fmaf(sc, a2, b.z), 0.f) * sc;
      a3 = fmaxf(fmaf(sc, a3, b.w), 0.f) * sc;
    } else {
      a0 *= sc; a1 *= sc; a2 *= sc; a3 *= sc;
    }
    stnt_u2(out + (size_t)n * 64 + c * 2, pack_bf2(a0, a1), pack_bf2(a2, a3));
  }
}

// ---------------- launch ----------------
extern "C" void kernel_launch(void* const* d_in, const int* in_sizes, int n_in,
                              void* d_out, int out_size, void* d_ws, size_t ws_size,
                              hipStream_t stream) {
  const float* x  = (const float*)d_in[0];
  const int*   ei = (const int*)d_in[1];
  const float* W1 = (const float*)d_in[2];
  const float* b1 = (const float*)d_in[3];
  const float* W3 = (const float*)d_in[4];
  const float* b3 = (const float*)d_in[5];
  const float* W4 = (const float*)d_in[6];
  const float* b4 = (const float*)d_in[7];

  const int N = in_sizes[0] / 128;
  const int E = in_sizes[1] / 2;
  const int* src = ei;
  const int* dst = ei + E;
  const bool small = (N <= 65535);
  const size_t esz = small ? sizeof(ushort_t) : sizeof(int);

  // buckets: ranges of (1<<shift) nodes, at most 512 buckets (LDS histogram size)
  int shift = 7;
  while (((N + (1 << shift) - 1) >> shift) > 512) ++shift;
  const int NB = (N + (1 << shift) - 1) >> shift;
  const int C = (E / NB) * 3 / 2 + 512;  // per-bucket capacity, ~1.5x mean + slack

  char* w = (char*)d_ws;
  size_t off = 0;
  auto carve = [&](size_t bytes) { void* p = w + off; off = align256(off + bytes); return p; };
  int*      deg       = (int*)carve((size_t)N * sizeof(int));
  int*      bucketcnt = (int*)carve(512 * sizeof(int));
  uint2*    buckets   = (uint2*)carve((size_t)NB * C * sizeof(uint2));
  void*     edge      = carve((size_t)N * MAXDEG * esz);
  uint_t*   bufG      = (uint_t*)carve((size_t)N * 64 * sizeof(uint_t));  // [N,128] bf16
  uint_t*   bufH      = (uint_t*)carve((size_t)N * 64 * sizeof(uint_t));
  ushort_t* B1hi      = (ushort_t*)carve((size_t)16384 * sizeof(ushort_t));
  ushort_t* B1lo      = (ushort_t*)carve((size_t)16384 * sizeof(ushort_t));
  ushort_t* B2hi      = (ushort_t*)carve((size_t)16384 * sizeof(ushort_t));
  ushort_t* B2lo      = (ushort_t*)carve((size_t)16384 * sizeof(ushort_t));

  float* out_mean = (float*)d_out;
  float* out_std  = out_mean + (size_t)N * 64;

  const int gblocks = (N + 63) / 64;
  const int ablocks = (N + 3) / 4;
  const int sblocks = (E + 2047) / 2048;

  pack_w_kernel<<<16, 256, 0, stream>>>(W1, W3, W4, B1hi, B1lo, B2hi, B2lo, bucketcnt);
  bucket_scatter_kernel<<<sblocks, 256, 0, stream>>>(src, dst, buckets, bucketcnt, E, C, shift, NB);

  if (small) {
    ushort_t* es = (ushort_t*)edge;
    bucket_to_rows_kernel<ushort_t, 128><<<NB, 256, 0, stream>>>(
        buckets, bucketcnt, es, deg, N, C, shift);
    gemm1_mfma_kernel<<<gblocks, 256, 0, stream>>>(x, B1hi, B1lo, (ushort_t*)bufG, N);
    aggregate_kernel<1, true,  ushort_t><<<ablocks, 256, 0, stream>>>(bufG, deg, es, b1, bufH, N);
    aggregate_kernel<2, false, ushort_t><<<ablocks, 256, 0, stream>>>(bufH, deg, es, nullptr, bufG, N);
  } else {
    int* es = (int*)edge;
    bucket_to_rows_kernel<int, 128><<<NB, 256, 0, stream>>>(
        buckets, bucketcnt, es, deg, N, C, shift);
    gemm1_mfma_kernel<<<gblocks, 256, 0, stream>>>(x, B1hi, B1lo, (ushort_t*)bufG, N);
    aggregate_kernel<1, true,  int><<<ablocks, 256, 0, stream>>>(bufG, deg, es, b1, bufH, N);
    aggregate_kernel<2, false, int><<<ablocks, 256, 0, stream>>>(bufH, deg, es, nullptr, bufG, N);
  }
  gemm2_mfma_kernel<<<gblocks, 256, 0, stream>>>(
      (const ushort_t*)bufG, B2hi, B2lo, b3, b4, out_mean, out_std, N);
}